// Round 12
// baseline (147.224 us; speedup 1.0000x reference)
//
#include <hip/hip_runtime.h>

#define F_IN 165
#define HID  32
#define TROWS 16                 // N=500000 = 16*31250 exact
#define XSRC  10560              // x source bytes per tile (16*660)
#define HCB   2048               // h/c source bytes per tile (16*128)
// padded LDS tile: x [16][688]=11008, h [16][144]=2304, c [16][128]=2048
#define HOFF  11008
#define COFF  (HOFF + 2304)      // 13312
#define BUFSZ (COFF + 2048)      // 15360
#define RING  3
#define PYOFF (RING * BUFSZ)     // 46080; +256 py -> 46336 B LDS (3 blocks/CU)

typedef __attribute__((ext_vector_type(8))) __bf16 bf16x8;
typedef __attribute__((ext_vector_type(4))) float  f32x4;

typedef __attribute__((address_space(1))) void as1_void;
typedef __attribute__((address_space(3))) void as3_void;

__device__ __forceinline__ void gload_lds16(const void* g, void* l) {
    __builtin_amdgcn_global_load_lds(
        reinterpret_cast<as1_void*>(reinterpret_cast<uintptr_t>(g)),
        reinterpret_cast<as3_void*>((uint32_t)reinterpret_cast<uintptr_t>(l)),
        16, 0, 0);
}
__device__ __forceinline__ void gload_lds4(const void* g, void* l) {
    __builtin_amdgcn_global_load_lds(
        reinterpret_cast<as1_void*>(reinterpret_cast<uintptr_t>(g)),
        reinterpret_cast<as3_void*>((uint32_t)reinterpret_cast<uintptr_t>(l)),
        4, 0, 0);
}

__device__ __forceinline__ float fast_sigmoid(float x) {
    return __builtin_amdgcn_rcpf(1.f + __builtin_amdgcn_exp2f(-1.4426950408889634f * x));
}
__device__ __forceinline__ float fast_tanh(float x) {
    return 1.f - 2.f * __builtin_amdgcn_rcpf(1.f + __builtin_amdgcn_exp2f(2.8853900817779268f * x));
}

// ---- workspace (prepacked): frag table 56 slots x 64 lanes x 16B; bias at +57344
#define FRAG_BYTES 57344

struct PrepParams {
    const float *W0, *W1, *W2, *W3;
    const float *Wc0, *Wc1, *Wc2, *Wc3;
    const float *b0, *b1, *b2, *b3;
    const float *bc0, *bc1, *bc2, *bc3;
    char* ws;
};

__global__ void gclstm_prep(PrepParams pp) {
    int t = blockIdx.x * 256 + threadIdx.x;
    if (t < 56 * 64) {
        int slot = t >> 6, l = t & 63;
        int ks = slot >> 3, g = (slot >> 1) & 3, hf = slot & 1;
        int cl = l & 15, q = l >> 4;
        const float* W = (ks < 6)
            ? (g==0 ? pp.W0  : g==1 ? pp.W1  : g==2 ? pp.W2  : pp.W3)
            : (g==0 ? pp.Wc0 : g==1 ? pp.Wc1 : g==2 ? pp.Wc2 : pp.Wc3);
        bf16x8 v;
#pragma unroll
        for (int j = 0; j < 8; ++j) {
            float f = 0.f;
            if (ks < 6) {
                int k = ks * 32 + q * 8 + j;
                if (k < F_IN) f = W[k * HID + hf * 16 + cl];
            } else {
                int k = q * 8 + j;
                f = W[k * HID + hf * 16 + cl];
            }
            v[j] = (__bf16)f;
        }
        *(bf16x8*)(pp.ws + slot * 1024 + l * 16) = v;
    } else if (t < 56 * 64 + 128) {
        int i = t - 56 * 64;
        int g = i >> 5, col = i & 31;
        const float* B  = g==0 ? pp.b0  : g==1 ? pp.b1  : g==2 ? pp.b2  : pp.b3;
        const float* Bc = g==0 ? pp.bc0 : g==1 ? pp.bc1 : g==2 ? pp.bc2 : pp.bc3;
        ((float*)(pp.ws + FRAG_BYTES))[i] = B[col] + Bc[col];
    }
}

struct Params {
    const float *x, *h, *c, *Wl, *bl;
    const char* ws;
    float *y, *h0o, *c0o;
    int n, nt;
};

// within-tile source offset for padded-x dest byte o (o < 11008):
//   r = o/688 (exact magic: 688r>>4 = 43r integral), col = o-688r;
//   col==672 is pad (clamp src 0); col==656 straddles 12B into next row (ok).
__device__ __forceinline__ int xsrc_off(int o) {
    int r = ((o >> 4) * 1525) >> 16;
    int col = o - 688 * r;
    return (col >= 660) ? 0 : (o - 28 * r);
}
// for padded-h dest byte o (o < 2304): r = o/144, col = o-144r; col>=128 pad.
__device__ __forceinline__ int hsrc_off(int o) {
    int r = ((o >> 4) * 7282) >> 16;
    int col = o - 144 * r;
    return (col >= 128) ? 0 : (o - 16 * r);
}

// 128 thr = 2 waves (hf halves); each wave: 16 rows x 16 cols x all 4 gates.
// 3-slot ring, depth-2: stage(t+2) issued at iter top; wait vmcnt(25) ==
// stage(t) complete (per-wave ops/iter = 8 stage + 9 stores; younger at wait
// = stage(t+1) 8 + stores 9 + stage(t+2) 8 = 25). 3 blocks/CU.
__global__ __launch_bounds__(128, 2) void gclstm_main(Params p) {
    __shared__ char smem[PYOFF + 256];
    float* py = (float*)(smem + PYOFF);   // [hf][16 rows][2 cls]

    const int tid = threadIdx.x;
    const int w   = tid >> 6;             // wave id == hf
    const int l   = tid & 63;
    const int cl  = l & 15, q = l >> 4;
    const int col = w * 16 + cl;

    // ---- weight fragments: this hf, all 4 gates ----
    bf16x8 bw[4][7];
#pragma unroll
    for (int ks = 0; ks < 7; ++ks)
#pragma unroll
        for (int g = 0; g < 4; ++g)
            bw[g][ks] = *(const bf16x8*)(p.ws + (ks * 8 + g * 2 + w) * 1024 + l * 16);

    const float* biasT = (const float*)(p.ws + FRAG_BYTES);
    float bias[4];
#pragma unroll
    for (int g = 0; g < 4; ++g) bias[g] = biasT[g * 32 + col];
    const float wl0 = p.Wl[col * 2 + 0];
    const float wl1 = p.Wl[col * 2 + 1];
    const float bl0 = p.bl[0], bl1 = p.bl[1];

    // ---- precompute per-lane tile-invariant staging source offsets ----
    // w0: x units 0-7.  w1: x units 8,9 + partial 10 (l<48) + h 2 full +
    //     h tail (4B) + c 2 direct.  8 ops per wave per tile, always issued.
    int s0, s1, s2, s3, s4, s5, s6, s7;   // generic src offsets per op
    if (w == 0) {
        s0 = xsrc_off(0 * 1024 + l * 16);
        s1 = xsrc_off(1 * 1024 + l * 16);
        s2 = xsrc_off(2 * 1024 + l * 16);
        s3 = xsrc_off(3 * 1024 + l * 16);
        s4 = xsrc_off(4 * 1024 + l * 16);
        s5 = xsrc_off(5 * 1024 + l * 16);
        s6 = xsrc_off(6 * 1024 + l * 16);
        s7 = xsrc_off(7 * 1024 + l * 16);
    } else {
        s0 = xsrc_off(8 * 1024 + l * 16);
        s1 = xsrc_off(9 * 1024 + l * 16);
        s2 = (l < 48) ? xsrc_off(10 * 1024 + l * 16) : 0;
        s3 = hsrc_off(0 * 1024 + l * 16);
        s4 = hsrc_off(1 * 1024 + l * 16);
        s5 = hsrc_off(2048 + l * 4);
        s6 = 0 * 1024 + l * 16;           // c direct
        s7 = 1 * 1024 + l * 16;
    }

    const int nt = p.nt, stride = gridDim.x;
    int t = blockIdx.x;
    if (t >= nt) return;

    // staging macro-equivalent: issue this wave's 8 ops for tile tt into buf
    auto stage = [&](char* buf, long tt) {
        const char* xb = (const char*)p.x + tt * (long)XSRC;
        if (w == 0) {
            gload_lds16(xb + s0, buf + 0 * 1024 + l * 16);
            gload_lds16(xb + s1, buf + 1 * 1024 + l * 16);
            gload_lds16(xb + s2, buf + 2 * 1024 + l * 16);
            gload_lds16(xb + s3, buf + 3 * 1024 + l * 16);
            gload_lds16(xb + s4, buf + 4 * 1024 + l * 16);
            gload_lds16(xb + s5, buf + 5 * 1024 + l * 16);
            gload_lds16(xb + s6, buf + 6 * 1024 + l * 16);
            gload_lds16(xb + s7, buf + 7 * 1024 + l * 16);
        } else {
            const char* hb = (const char*)p.h + tt * (long)HCB;
            const char* cb = (const char*)p.c + tt * (long)HCB;
            gload_lds16(xb + s0, buf + 8 * 1024 + l * 16);
            gload_lds16(xb + s1, buf + 9 * 1024 + l * 16);
            if (l < 48)  // dest past x region otherwise; exec!=0 so still counted
                gload_lds16(xb + s2, buf + 10 * 1024 + l * 16);
            else
                gload_lds16(xb + 0, buf + 10 * 1024 + 752);  // keep count uniform; dest is pad byte (row15 col 736>? no: 10240+752=10992 col 672 pad)
            gload_lds16(hb + s3, buf + HOFF + 0 * 1024 + l * 16);
            gload_lds16(hb + s4, buf + HOFF + 1 * 1024 + l * 16);
            gload_lds4 (hb + s5, buf + HOFF + 2048 + l * 4);
            gload_lds16(cb + s6, buf + COFF + 0 * 1024 + l * 16);
            gload_lds16(cb + s7, buf + COFF + 1 * 1024 + l * 16);
        }
    };

    // ---- prologue: stage tiles t, t+1 into slots 0,1; drain ----
    {
        long t1 = t + stride;
        stage(smem + 0 * BUFSZ, t);
        stage(smem + 1 * BUFSZ, t1 < nt ? t1 : 0);
    }
    asm volatile("s_waitcnt vmcnt(0)" ::: "memory");
    __builtin_amdgcn_s_barrier();
    asm volatile("" ::: "memory");

    int cur = 0;
    while (true) {
        // ---- stage t+2 into the slot consumed two iters ago ----
        {
            int c2 = cur + 2; if (c2 >= RING) c2 -= RING;
            long t2 = (long)t + 2 * stride;
            stage(smem + c2 * BUFSZ, t2 < nt ? t2 : 0);
        }
        // ---- wait for OWN stage(t), then barrier (cross-wave visibility) ----
        asm volatile("s_waitcnt vmcnt(25)" ::: "memory");
        __builtin_amdgcn_s_barrier();
        asm volatile("" ::: "memory");

        // ---- consume slot cur (tile t) ----
        const char* buf  = smem + cur * BUFSZ;
        const char* xrow = buf + cl * 688;
        f32x4 acc[4];
#pragma unroll
        for (int g = 0; g < 4; ++g) acc[g] = (f32x4){0.f, 0.f, 0.f, 0.f};
#pragma unroll
        for (int ks = 0; ks < 5; ++ks) {
            float4 a = *(const float4*)(xrow + ks * 128 + q * 32);
            float4 b = *(const float4*)(xrow + ks * 128 + q * 32 + 16);
            bf16x8 af;
            af[0]=(__bf16)a.x; af[1]=(__bf16)a.y; af[2]=(__bf16)a.z; af[3]=(__bf16)a.w;
            af[4]=(__bf16)b.x; af[5]=(__bf16)b.y; af[6]=(__bf16)b.z; af[7]=(__bf16)b.w;
#pragma unroll
            for (int g = 0; g < 4; ++g)
                acc[g] = __builtin_amdgcn_mfma_f32_16x16x32_bf16(af, bw[g][ks], acc[g], 0, 0, 0);
        }
        {   // ks=5 tail: k=160..164 on q==0 lanes (bytes 640-659)
            float4 tq = *(const float4*)(xrow + 640);
            float t4  = *(const float*)(xrow + 656);
            bool qz = (q == 0);
            bf16x8 af;
            af[0] = (__bf16)(qz ? tq.x : 0.f);
            af[1] = (__bf16)(qz ? tq.y : 0.f);
            af[2] = (__bf16)(qz ? tq.z : 0.f);
            af[3] = (__bf16)(qz ? tq.w : 0.f);
            af[4] = (__bf16)(qz ? t4   : 0.f);
            af[5] = (__bf16)0.f; af[6] = (__bf16)0.f; af[7] = (__bf16)0.f;
#pragma unroll
            for (int g = 0; g < 4; ++g)
                acc[g] = __builtin_amdgcn_mfma_f32_16x16x32_bf16(af, bw[g][5], acc[g], 0, 0, 0);
        }
        {   // h fragment: padded 144B rows, conflict-free b128
            const char* hrow = buf + HOFF + cl * 144;
            float4 a = *(const float4*)(hrow + q * 32);
            float4 b = *(const float4*)(hrow + q * 32 + 16);
            bf16x8 af;
            af[0]=(__bf16)a.x; af[1]=(__bf16)a.y; af[2]=(__bf16)a.z; af[3]=(__bf16)a.w;
            af[4]=(__bf16)b.x; af[5]=(__bf16)b.y; af[6]=(__bf16)b.z; af[7]=(__bf16)b.w;
#pragma unroll
            for (int g = 0; g < 4; ++g)
                acc[g] = __builtin_amdgcn_mfma_f32_16x16x32_bf16(af, bw[g][6], acc[g], 0, 0, 0);
        }

        // ---- epilogue: exactly 8 global stores + py writes ----
        const long gbase = (long)t * TROWS;
#pragma unroll
        for (int jj = 0; jj < 4; ++jj) {
            const int r = 4 * q + jj;
            float iv = fast_sigmoid(acc[0][jj] + bias[0]);
            float fv = fast_sigmoid(acc[1][jj] + bias[1]);
            float gv = fast_tanh   (acc[2][jj] + bias[2]);
            float ov = fast_sigmoid(acc[3][jj] + bias[3]);
            float cvv = *(const float*)(buf + COFF + r * 128 + col * 4);
            float c0 = fv * cvv + iv * gv;
            float h0 = ov * fast_tanh(c0);
            long grow = gbase + r;
            p.c0o[grow * HID + col] = c0;
            p.h0o[grow * HID + col] = h0;
            float rl = fmaxf(h0, 0.f);
            float r0 = rl * wl0, r1 = rl * wl1;
            r0 += __shfl_xor(r0, 1); r0 += __shfl_xor(r0, 2);
            r0 += __shfl_xor(r0, 4); r0 += __shfl_xor(r0, 8);
            r1 += __shfl_xor(r1, 1); r1 += __shfl_xor(r1, 2);
            r1 += __shfl_xor(r1, 4); r1 += __shfl_xor(r1, 8);
            if (cl == 0) {
                py[(w * 16 + r) * 2 + 0] = r0;
                py[(w * 16 + r) * 2 + 1] = r1;
            }
        }
        asm volatile("s_waitcnt lgkmcnt(0)" ::: "memory");
        __builtin_amdgcn_s_barrier();   // py visible; also fences slot reuse
        asm volatile("" ::: "memory");

        // ---- y: wave w stores values v = w*16 + l (1 store per wave) ----
        if (l < 16) {
            int v = w * 16 + l;
            int r = v >> 1, k = v & 1;
            float yv = py[r * 2 + k] + py[32 + r * 2 + k] + (k ? bl1 : bl0);
            p.y[gbase * 2 + v] = yv;
        }

        t += stride;
        if (t >= nt) break;
        cur = cur + 1; if (cur >= RING) cur -= RING;
    }
}

extern "C" void kernel_launch(void* const* d_in, const int* in_sizes, int n_in,
                              void* d_out, int out_size, void* d_ws, size_t ws_size,
                              hipStream_t stream) {
    PrepParams pp;
    pp.W0  = (const float*)d_in[5];
    pp.W1  = (const float*)d_in[6];
    pp.W2  = (const float*)d_in[7];
    pp.W3  = (const float*)d_in[8];
    pp.b0  = (const float*)d_in[9];
    pp.b1  = (const float*)d_in[10];
    pp.b2  = (const float*)d_in[11];
    pp.b3  = (const float*)d_in[12];
    pp.Wc0 = (const float*)d_in[13];
    pp.Wc1 = (const float*)d_in[14];
    pp.Wc2 = (const float*)d_in[15];
    pp.Wc3 = (const float*)d_in[16];
    pp.bc0 = (const float*)d_in[17];
    pp.bc1 = (const float*)d_in[18];
    pp.bc2 = (const float*)d_in[19];
    pp.bc3 = (const float*)d_in[20];
    pp.ws  = (char*)d_ws;
    hipLaunchKernelGGL(gclstm_prep, dim3(15), dim3(256), 0, stream, pp);

    Params p;
    p.x  = (const float*)d_in[0];
    p.h  = (const float*)d_in[3];
    p.c  = (const float*)d_in[4];
    p.Wl = (const float*)d_in[21];
    p.bl = (const float*)d_in[22];
    p.ws = (const char*)d_ws;

    const int n = in_sizes[0] / F_IN;   // 500000 (divisible by TROWS)
    p.n  = n;
    p.nt = n / TROWS;                   // 31250

    float* out = (float*)d_out;
    p.y   = out;
    p.h0o = out + (long)n * 2;
    p.c0o = out + (long)n * 2 + (long)n * HID;

    // 3 blocks/CU x 256 CUs (LDS 46336 -> 3 fit), depth-2 ring
    hipLaunchKernelGGL(gclstm_main, dim3(768), dim3(128), 0, stream, p);
}

// Round 13
// 131.624 us; speedup vs baseline: 1.1185x; 1.1185x over previous
//
#include <hip/hip_runtime.h>

#define F_IN 165
#define HID  32
#define TROWS 32                        // rows per tile; N=500000 = 32*15625 exact
#define XBYTES (TROWS * F_IN * 4)       // 21120
#define XUNITS 21                       // ceil(21120/1024); unit 20 overreads 384B
#define HCBYTES (TROWS * HID * 4)       // 4096
#define HOFF   (XUNITS * 1024)          // 21504
#define COFF   (HOFF + HCBYTES)         // 25600
#define BUFSZ  (COFF + HCBYTES)         // 29696
#define PYOFF  (2 * BUFSZ)              // 59392; +512 py -> 59904 B LDS total

typedef __attribute__((ext_vector_type(8))) __bf16 bf16x8;
typedef __attribute__((ext_vector_type(4))) float  f32x4;

typedef __attribute__((address_space(1))) void as1_void;
typedef __attribute__((address_space(3))) void as3_void;

__device__ __forceinline__ void gload_lds16(const void* g, void* l) {
    __builtin_amdgcn_global_load_lds(
        reinterpret_cast<as1_void*>(reinterpret_cast<uintptr_t>(g)),
        reinterpret_cast<as3_void*>((uint32_t)reinterpret_cast<uintptr_t>(l)),
        16, 0, 0);
}

__device__ __forceinline__ float fast_sigmoid(float x) {
    return __builtin_amdgcn_rcpf(1.f + __builtin_amdgcn_exp2f(-1.4426950408889634f * x));
}
__device__ __forceinline__ float fast_tanh(float x) {
    return 1.f - 2.f * __builtin_amdgcn_rcpf(1.f + __builtin_amdgcn_exp2f(2.8853900817779268f * x));
}

// ---- workspace (prepacked): frag table 56 slots x 64 lanes x 16B; bias at +57344
#define FRAG_BYTES 57344

struct PrepParams {
    const float *W0, *W1, *W2, *W3;
    const float *Wc0, *Wc1, *Wc2, *Wc3;
    const float *b0, *b1, *b2, *b3;
    const float *bc0, *bc1, *bc2, *bc3;
    char* ws;
};

__global__ void gclstm_prep(PrepParams pp) {
    int t = blockIdx.x * 256 + threadIdx.x;
    if (t < 56 * 64) {
        int slot = t >> 6, l = t & 63;
        int ks = slot >> 3, g = (slot >> 1) & 3, hf = slot & 1;
        int cl = l & 15, q = l >> 4;
        const float* W = (ks < 6)
            ? (g==0 ? pp.W0  : g==1 ? pp.W1  : g==2 ? pp.W2  : pp.W3)
            : (g==0 ? pp.Wc0 : g==1 ? pp.Wc1 : g==2 ? pp.Wc2 : pp.Wc3);
        bf16x8 v;
#pragma unroll
        for (int j = 0; j < 8; ++j) {
            float f = 0.f;
            if (ks < 6) {
                int k = ks * 32 + q * 8 + j;
                if (k < F_IN) f = W[k * HID + hf * 16 + cl];
            } else {
                int k = q * 8 + j;
                f = W[k * HID + hf * 16 + cl];
            }
            v[j] = (__bf16)f;
        }
        *(bf16x8*)(pp.ws + slot * 1024 + l * 16) = v;
    } else if (t < 56 * 64 + 128) {
        int i = t - 56 * 64;
        int g = i >> 5, col = i & 31;
        const float* B  = g==0 ? pp.b0  : g==1 ? pp.b1  : g==2 ? pp.b2  : pp.b3;
        const float* Bc = g==0 ? pp.bc0 : g==1 ? pp.bc1 : g==2 ? pp.bc2 : pp.bc3;
        ((float*)(pp.ws + FRAG_BYTES))[i] = B[col] + Bc[col];
    }
}

struct Params {
    const float *x, *h, *c, *Wl, *bl;
    const char* ws;
    float *y, *h0o, *c0o;
    int n, nt;
};

// Stage one 32-row tile (x 21120B raw-contiguous + h 4KB + c 4KB) into LDS
// buffer bb via global_load_lds. Waves 0-2: 7 x-units each; wave 3: h+c.
__device__ __forceinline__ void stage_tile(const Params& p, char* smem, int bb,
                                           int tt, int w, int l, bool last) {
    char* buf = smem + bb * BUFSZ;
    if (w < 3) {
        const char* xc = (const char*)p.x + (size_t)tt * XBYTES + (size_t)l * 16;
#pragma unroll
        for (int i = 0; i < 7; ++i) {
            int u = w * 7 + i;
            // unit 20 overreads 384B past the chunk (next tile's x) — harmless
            // except on the very last tile: mask lanes >= 40.
            if (u != 20 || !last || l < 40)
                gload_lds16(xc + u * 1024, buf + u * 1024);
        }
    } else {
        const char* hc = (const char*)p.h + (size_t)tt * HCBYTES + (size_t)l * 16;
        const char* cc = (const char*)p.c + (size_t)tt * HCBYTES + (size_t)l * 16;
#pragma unroll
        for (int i = 0; i < 4; ++i) {
            gload_lds16(hc + i * 1024, buf + HOFF + i * 1024);
            gload_lds16(cc + i * 1024, buf + COFF + i * 1024);
        }
    }
}

// 256 threads = 4 waves = {sub rows-half} x {hf cols-half}; each wave: 16 rows
// x 16 cols x all 4 gates. Exactly 9 vmem stores per wave per tile (8 c0/h0 +
// 1 y) -> end-of-iter s_waitcnt vmcnt(9) waits precisely for next-tile staging.
__global__ __launch_bounds__(256, 2) void gclstm_main(Params p) {
    __shared__ char smem[PYOFF + 512];
    float* py = (float*)(smem + PYOFF);   // [subwave 0..3][16 rows][2 cls]

    const int tid = threadIdx.x;
    const int w   = tid >> 6;
    const int sub = w >> 1, hf = w & 1;
    const int l   = tid & 63;
    const int cl  = l & 15, q = l >> 4;
    const int col = hf * 16 + cl;

    // weight fragments: this hf, all 4 gates (28 coalesced dwordx4)
    bf16x8 bw[4][7];
#pragma unroll
    for (int ks = 0; ks < 7; ++ks)
#pragma unroll
        for (int g = 0; g < 4; ++g)
            bw[g][ks] = *(const bf16x8*)(p.ws + (ks * 8 + g * 2 + hf) * 1024 + l * 16);

    const float* biasT = (const float*)(p.ws + FRAG_BYTES);
    float bias[4];
#pragma unroll
    for (int g = 0; g < 4; ++g) bias[g] = biasT[g * 32 + col];
    const float wl0 = p.Wl[col * 2 + 0];
    const float wl1 = p.Wl[col * 2 + 1];
    const float bl0 = p.bl[0], bl1 = p.bl[1];

    const int nt = p.nt, stride = gridDim.x;
    int t = blockIdx.x;
    if (t >= nt) return;

    // prologue: stage first tile, drain once
    stage_tile(p, smem, 0, t, w, l, t == nt - 1);
    asm volatile("s_waitcnt vmcnt(0)" ::: "memory");
    __builtin_amdgcn_s_barrier();
    asm volatile("" ::: "memory");

    int cur = 0;
    while (true) {
        const int tn = t + stride;
        const bool more = (tn < nt);
        if (more) stage_tile(p, smem, cur ^ 1, tn, w, l, tn == nt - 1);   // prefetch

        // ---- consume buf[cur] ----
        const char*  buf = smem + cur * BUFSZ;
        const float* xb  = (const float*)buf;
        const float* hb  = (const float*)(buf + HOFF);
        const float* cb  = (const float*)(buf + COFF);
        const int lrow = sub * 16 + cl;
        const int rb   = lrow * F_IN;

        bf16x8 af[7];
#pragma unroll
        for (int ks = 0; ks < 5; ++ks) {
            float v[8];
#pragma unroll
            for (int j = 0; j < 8; ++j) v[j] = xb[rb + ks * 32 + q * 8 + j];
#pragma unroll
            for (int j = 0; j < 8; ++j) af[ks][j] = (__bf16)v[j];
        }
        {   // ks=5 tail: k=160..164 on q==0 lanes; mask others (stale-LDS safety)
            bool qz = (q == 0);
            float t0 = xb[rb + 160], t1 = xb[rb + 161], t2 = xb[rb + 162];
            float t3 = xb[rb + 163], t4 = xb[rb + 164];
            af[5][0] = (__bf16)(qz ? t0 : 0.f);
            af[5][1] = (__bf16)(qz ? t1 : 0.f);
            af[5][2] = (__bf16)(qz ? t2 : 0.f);
            af[5][3] = (__bf16)(qz ? t3 : 0.f);
            af[5][4] = (__bf16)(qz ? t4 : 0.f);
            af[5][5] = (__bf16)0.f; af[5][6] = (__bf16)0.f; af[5][7] = (__bf16)0.f;
        }
        {   // h fragment: 16B-aligned LDS b128 x2
            const float* hr = hb + lrow * HID + q * 8;
            float4 hA = *(const float4*)hr;
            float4 hB = *(const float4*)(hr + 4);
            af[6][0]=(__bf16)hA.x; af[6][1]=(__bf16)hA.y; af[6][2]=(__bf16)hA.z; af[6][3]=(__bf16)hA.w;
            af[6][4]=(__bf16)hB.x; af[6][5]=(__bf16)hB.y; af[6][6]=(__bf16)hB.z; af[6][7]=(__bf16)hB.w;
        }

        f32x4 acc[4];
#pragma unroll
        for (int g = 0; g < 4; ++g) acc[g] = (f32x4){0.f, 0.f, 0.f, 0.f};
#pragma unroll
        for (int ks = 0; ks < 7; ++ks)
#pragma unroll
            for (int g = 0; g < 4; ++g)
                acc[g] = __builtin_amdgcn_mfma_f32_16x16x32_bf16(af[ks], bw[g][ks], acc[g], 0, 0, 0);

        // ---- epilogue: exactly 8 global stores + py LDS writes ----
        const int  drow  = sub * 16 + 4 * q;
        const long gbase = (long)t * TROWS;
#pragma unroll
        for (int jj = 0; jj < 4; ++jj) {
            float iv = fast_sigmoid(acc[0][jj] + bias[0]);
            float fv = fast_sigmoid(acc[1][jj] + bias[1]);
            float gv = fast_tanh   (acc[2][jj] + bias[2]);
            float ov = fast_sigmoid(acc[3][jj] + bias[3]);
            float cvv = cb[(drow + jj) * HID + col];
            float c0 = fv * cvv + iv * gv;
            float h0 = ov * fast_tanh(c0);
            long grow = gbase + drow + jj;
            p.c0o[grow * HID + col] = c0;
            p.h0o[grow * HID + col] = h0;
            float rl = fmaxf(h0, 0.f);
            float r0 = rl * wl0, r1 = rl * wl1;
            r0 += __shfl_xor(r0, 1); r0 += __shfl_xor(r0, 2);
            r0 += __shfl_xor(r0, 4); r0 += __shfl_xor(r0, 8);
            r1 += __shfl_xor(r1, 1); r1 += __shfl_xor(r1, 2);
            r1 += __shfl_xor(r1, 4); r1 += __shfl_xor(r1, 8);
            if (cl == 0) {
                py[((sub * 2 + hf) * 16 + 4 * q + jj) * 2 + 0] = r0;
                py[((sub * 2 + hf) * 16 + 4 * q + jj) * 2 + 1] = r1;
            }
        }
        asm volatile("s_waitcnt lgkmcnt(0)" ::: "memory");
        __builtin_amdgcn_s_barrier();
        asm volatile("" ::: "memory");
        // ---- y: wave w stores values v = w*16 + l (1 store inst per wave) ----
        if (l < 16) {
            int v = w * 16 + l;
            int r = v >> 1, k = v & 1;
            int s2 = r >> 4, r16 = r & 15;
            float yv = py[((s2 * 2 + 0) * 16 + r16) * 2 + k]
                     + py[((s2 * 2 + 1) * 16 + r16) * 2 + k]
                     + (k ? bl1 : bl0);
            p.y[gbase * 2 + v] = yv;
        }

        if (!more) break;
        // wait: everything older than the 9 stores (== this iter's staging) done
        asm volatile("s_waitcnt vmcnt(9)" ::: "memory");
        __builtin_amdgcn_s_barrier();
        asm volatile("" ::: "memory");
        cur ^= 1; t = tn;
    }
}

extern "C" void kernel_launch(void* const* d_in, const int* in_sizes, int n_in,
                              void* d_out, int out_size, void* d_ws, size_t ws_size,
                              hipStream_t stream) {
    PrepParams pp;
    pp.W0  = (const float*)d_in[5];
    pp.W1  = (const float*)d_in[6];
    pp.W2  = (const float*)d_in[7];
    pp.W3  = (const float*)d_in[8];
    pp.b0  = (const float*)d_in[9];
    pp.b1  = (const float*)d_in[10];
    pp.b2  = (const float*)d_in[11];
    pp.b3  = (const float*)d_in[12];
    pp.Wc0 = (const float*)d_in[13];
    pp.Wc1 = (const float*)d_in[14];
    pp.Wc2 = (const float*)d_in[15];
    pp.Wc3 = (const float*)d_in[16];
    pp.bc0 = (const float*)d_in[17];
    pp.bc1 = (const float*)d_in[18];
    pp.bc2 = (const float*)d_in[19];
    pp.bc3 = (const float*)d_in[20];
    pp.ws  = (char*)d_ws;
    hipLaunchKernelGGL(gclstm_prep, dim3(15), dim3(256), 0, stream, pp);

    Params p;
    p.x  = (const float*)d_in[0];
    p.h  = (const float*)d_in[3];
    p.c  = (const float*)d_in[4];
    p.Wl = (const float*)d_in[21];
    p.bl = (const float*)d_in[22];
    p.ws = (const char*)d_ws;

    const int n = in_sizes[0] / F_IN;   // 500000 (assumed divisible by TROWS)
    p.n  = n;
    p.nt = n / TROWS;                   // 15625 exact

    float* out = (float*)d_out;
    p.y   = out;
    p.h0o = out + (long)n * 2;
    p.c0o = out + (long)n * 2 + (long)n * HID;

    hipLaunchKernelGGL(gclstm_main, dim3(1024), dim3(256), 0, stream, p);
}